// Round 1
// baseline (303.568 us; speedup 1.0000x reference)
//
#include <hip/hip_runtime.h>

typedef __attribute__((ext_vector_type(4))) float f32x4;
typedef __attribute__((ext_vector_type(8))) short bf16x8;

__device__ __forceinline__ ushort f2bf(float f) {
  union { float f; unsigned u; } v; v.f = f;
  unsigned u = v.u;
  return (ushort)((u + 0x7fffu + ((u >> 16) & 1u)) >> 16);
}

// ---------------- X fp32 -> bf16 ----------------
__global__ __launch_bounds__(256) void cvt_x(const float* __restrict__ x,
                                             ushort* __restrict__ o) {
  int idx = blockIdx.x * 256 + threadIdx.x;          // 4 floats per thread
  float4 v = reinterpret_cast<const float4*>(x)[idx];
  ushort4 r;
  r.x = f2bf(v.x); r.y = f2bf(v.y); r.z = f2bf(v.z); r.w = f2bf(v.w);
  reinterpret_cast<ushort4*>(o)[idx] = r;
}

// ---------------- W fp32 [K][N] -> bf16 W^T [3][N][K] ----------------
__global__ __launch_bounds__(256) void wtrans(const float* __restrict__ Wq,
                                              const float* __restrict__ Wk,
                                              const float* __restrict__ Wv,
                                              ushort* __restrict__ WT) {
  __shared__ ushort tile[64 * 65];
  int bx = blockIdx.x;
  int w = bx >> 8;            // 0..2
  int rem = bx & 255;
  int k0 = (rem >> 4) << 6;
  int n0 = (rem & 15) << 6;
  const float* W = (w == 0) ? Wq : (w == 1) ? Wk : Wv;
  int tid = threadIdx.x;
#pragma unroll
  for (int it = 0; it < 16; ++it) {
    int idx = tid + it * 256;
    int r = idx >> 6, c = idx & 63;
    tile[r * 65 + c] = f2bf(W[(k0 + r) * 1024 + n0 + c]);
  }
  __syncthreads();
#pragma unroll
  for (int it = 0; it < 16; ++it) {
    int idx = tid + it * 256;
    int r = idx >> 6, c = idx & 63;
    WT[w * 1048576 + (n0 + r) * 1024 + k0 + c] = tile[c * 65 + r];
  }
}

// ---------------- fused QKV GEMM: Y = Xb * W + b, write [B,h,S,d] bf16 -------
// grid: (M/64, 3N/64) = (64, 48); block 256 (4 waves, each 16 rows x 64 cols)
__global__ __launch_bounds__(256) void qkv_gemm(
    const ushort* __restrict__ Xb, const ushort* __restrict__ WT,
    const float* __restrict__ bq, const float* __restrict__ bk,
    const float* __restrict__ bv, ushort* __restrict__ Qb,
    ushort* __restrict__ Kb, ushort* __restrict__ Vb) {
  __shared__ ushort Xs[64 * 72];
  __shared__ ushort Wsm[64 * 72];
  int tid = threadIdx.x;
  int wave = tid >> 6, lane = tid & 63, g = lane >> 4, lr = lane & 15;
  int m0 = blockIdx.x << 6;
  int n0g = blockIdx.y << 6;
  f32x4 acc[4];
#pragma unroll
  for (int i = 0; i < 4; ++i) { acc[i][0] = 0.f; acc[i][1] = 0.f; acc[i][2] = 0.f; acc[i][3] = 0.f; }

  for (int k0 = 0; k0 < 1024; k0 += 64) {
#pragma unroll
    for (int c = 0; c < 2; ++c) {
      int lin = tid + (c << 8);
      int row = lin >> 3, cc = lin & 7;
      *reinterpret_cast<uint4*>(&Xs[row * 72 + cc * 8]) =
          *reinterpret_cast<const uint4*>(&Xb[(m0 + row) * 1024 + k0 + cc * 8]);
      *reinterpret_cast<uint4*>(&Wsm[row * 72 + cc * 8]) =
          *reinterpret_cast<const uint4*>(&WT[(n0g + row) * 1024 + k0 + cc * 8]);
    }
    __syncthreads();
#pragma unroll
    for (int ks = 0; ks < 2; ++ks) {
      bf16x8 a = *reinterpret_cast<const bf16x8*>(&Xs[(wave * 16 + lr) * 72 + ks * 32 + g * 8]);
#pragma unroll
      for (int ns = 0; ns < 4; ++ns) {
        bf16x8 bfr = *reinterpret_cast<const bf16x8*>(&Wsm[(ns * 16 + lr) * 72 + ks * 32 + g * 8]);
        acc[ns] = __builtin_amdgcn_mfma_f32_16x16x32_bf16(a, bfr, acc[ns], 0, 0, 0);
      }
    }
    __syncthreads();
  }
  int which = n0g >> 10;
  const float* bias = (which == 0) ? bq : (which == 1) ? bk : bv;
  ushort* ob = (which == 0) ? Qb : (which == 1) ? Kb : Vb;
  int nn = n0g & 1023;
#pragma unroll
  for (int ns = 0; ns < 4; ++ns) {
    int n = nn + ns * 16 + lr;
    float bb = bias[n];
    int hh = n >> 6, dd = n & 63;
#pragma unroll
    for (int r = 0; r < 4; ++r) {
      int m = m0 + wave * 16 + g * 4 + r;
      int b_ = m >> 11, s = m & 2047;
      ob[((b_ * 16 + hh) * 2048 + s) * 64 + dd] = f2bf(acc[ns][r] + bb);
    }
  }
}

// ---------------- flash attention (causal) ----------------
// grid: (S/64, B*H) = (32, 32); block 256; wave w owns q rows [q0+16w, q0+16w+16)
__global__ __launch_bounds__(256) void attn(const ushort* __restrict__ Qb,
                                            const ushort* __restrict__ Kb,
                                            const ushort* __restrict__ Vb,
                                            const float* __restrict__ mask,
                                            float* __restrict__ out) {
  __shared__ ushort Ks[64 * 72];
  __shared__ ushort VsT[64 * 72];   // transposed: VsT[d][kv]
  __shared__ ushort Ps[4][16 * 72];
  int tid = threadIdx.x;
  int wave = tid >> 6, lane = tid & 63, g = lane >> 4, lr = lane & 15;
  int qt = blockIdx.x, bh = blockIdx.y;
  int b_ = bh >> 4, h = bh & 15;
  const ushort* Qh = Qb + (size_t)bh * 2048 * 64;
  const ushort* Kh = Kb + (size_t)bh * 2048 * 64;
  const ushort* Vh = Vb + (size_t)bh * 2048 * 64;
  int q0 = qt << 6;
  int qw = q0 + wave * 16;

  bf16x8 aq0 = *reinterpret_cast<const bf16x8*>(&Qh[(qw + lr) * 64 + g * 8]);
  bf16x8 aq1 = *reinterpret_cast<const bf16x8*>(&Qh[(qw + lr) * 64 + 32 + g * 8]);

  f32x4 o[4];
  float mrun[4], lrun[4];
#pragma unroll
  for (int i = 0; i < 4; ++i) {
    o[i][0] = 0.f; o[i][1] = 0.f; o[i][2] = 0.f; o[i][3] = 0.f;
    mrun[i] = -__builtin_inff();
    lrun[i] = 0.f;
  }

  int ntile = qt + 1;
  for (int t = 0; t < ntile; ++t) {
    int kv0 = t << 6;
#pragma unroll
    for (int c = 0; c < 2; ++c) {
      int lin = tid + (c << 8);
      int row = lin >> 3, cc = lin & 7;
      *reinterpret_cast<uint4*>(&Ks[row * 72 + cc * 8]) =
          *reinterpret_cast<const uint4*>(&Kh[(kv0 + row) * 64 + cc * 8]);
      uint4 vv = *reinterpret_cast<const uint4*>(&Vh[(kv0 + row) * 64 + cc * 8]);
      const ushort* vp = reinterpret_cast<const ushort*>(&vv);
#pragma unroll
      for (int i = 0; i < 8; ++i) VsT[(cc * 8 + i) * 72 + row] = vp[i];
    }
    __syncthreads();

    // QK^T: scores for 16 q rows x 64 kv
    f32x4 sc[4];
#pragma unroll
    for (int sub = 0; sub < 4; ++sub) {
      f32x4 s;
      s[0] = 0.f; s[1] = 0.f; s[2] = 0.f; s[3] = 0.f;
      bf16x8 bk0 = *reinterpret_cast<const bf16x8*>(&Ks[(sub * 16 + lr) * 72 + g * 8]);
      bf16x8 bk1 = *reinterpret_cast<const bf16x8*>(&Ks[(sub * 16 + lr) * 72 + 32 + g * 8]);
      s = __builtin_amdgcn_mfma_f32_16x16x32_bf16(aq0, bk0, s, 0, 0, 0);
      s = __builtin_amdgcn_mfma_f32_16x16x32_bf16(aq1, bk1, s, 0, 0, 0);
      int kk = kv0 + sub * 16 + lr;
      float mv = mask[b_ * 2048 + kk];
#pragma unroll
      for (int r = 0; r < 4; ++r) {
        int q = qw + g * 4 + r;
        float v = s[r] * 0.125f + mv;
        s[r] = (kk > q) ? -__builtin_inff() : v;
      }
      sc[sub] = s;
    }

    // online softmax per row (rows live on 16-lane groups)
    float alpha[4];
#pragma unroll
    for (int r = 0; r < 4; ++r) {
      float tm = fmaxf(fmaxf(sc[0][r], sc[1][r]), fmaxf(sc[2][r], sc[3][r]));
      tm = fmaxf(tm, __shfl_xor(tm, 1));
      tm = fmaxf(tm, __shfl_xor(tm, 2));
      tm = fmaxf(tm, __shfl_xor(tm, 4));
      tm = fmaxf(tm, __shfl_xor(tm, 8));
      float nm = fmaxf(mrun[r], tm);
      float al = __expf(mrun[r] - nm);   // -inf -> 0 on first tile
      float rs = 0.f;
#pragma unroll
      for (int sub = 0; sub < 4; ++sub) {
        float p = __expf(sc[sub][r] - nm);
        sc[sub][r] = p;
        rs += p;
      }
      rs += __shfl_xor(rs, 1);
      rs += __shfl_xor(rs, 2);
      rs += __shfl_xor(rs, 4);
      rs += __shfl_xor(rs, 8);
      lrun[r] = lrun[r] * al + rs;
      mrun[r] = nm;
      alpha[r] = al;
#pragma unroll
      for (int sub = 0; sub < 4; ++sub)
        Ps[wave][(g * 4 + r) * 72 + sub * 16 + lr] = f2bf(sc[sub][r]);
    }
#pragma unroll
    for (int ns = 0; ns < 4; ++ns) {
#pragma unroll
      for (int r = 0; r < 4; ++r) o[ns][r] *= alpha[r];
    }

    // PV: O += P * V
#pragma unroll
    for (int kc = 0; kc < 2; ++kc) {
      bf16x8 pa = *reinterpret_cast<const bf16x8*>(&Ps[wave][lr * 72 + kc * 32 + g * 8]);
#pragma unroll
      for (int ds_ = 0; ds_ < 4; ++ds_) {
        bf16x8 vb = *reinterpret_cast<const bf16x8*>(&VsT[(ds_ * 16 + lr) * 72 + kc * 32 + g * 8]);
        o[ds_] = __builtin_amdgcn_mfma_f32_16x16x32_bf16(pa, vb, o[ds_], 0, 0, 0);
      }
    }
    __syncthreads();
  }

#pragma unroll
  for (int ns = 0; ns < 4; ++ns) {
#pragma unroll
    for (int r = 0; r < 4; ++r) {
      int q = qw + g * 4 + r;
      out[(size_t)(b_ * 2048 + q) * 1024 + h * 64 + ns * 16 + lr] = o[ns][r] / lrun[r];
    }
  }
}

extern "C" void kernel_launch(void* const* d_in, const int* in_sizes, int n_in,
                              void* d_out, int out_size, void* d_ws, size_t ws_size,
                              hipStream_t stream) {
  const float* X    = (const float*)d_in[0];
  const float* mask = (const float*)d_in[1];
  const float* Wq   = (const float*)d_in[2];
  const float* bq   = (const float*)d_in[3];
  const float* Wk   = (const float*)d_in[4];
  const float* bk   = (const float*)d_in[5];
  const float* Wv   = (const float*)d_in[6];
  const float* bv   = (const float*)d_in[7];
  float* out = (float*)d_out;

  char* ws = (char*)d_ws;
  ushort* Xb  = (ushort*)ws;                         // 4096x1024 bf16 = 8 MB
  ushort* WTb = (ushort*)(ws + 8388608);             // 3x1024x1024 bf16 = 6 MB
  ushort* Qb  = (ushort*)(ws + 8388608 + 6291456);   // [B,h,S,d] bf16 = 8 MB
  ushort* Kb  = Qb + 4194304;
  ushort* Vb  = Kb + 4194304;

  cvt_x<<<4096, 256, 0, stream>>>(X, Xb);
  wtrans<<<768, 256, 0, stream>>>(Wq, Wk, Wv, WTb);
  qkv_gemm<<<dim3(64, 48), 256, 0, stream>>>(Xb, WTb, bq, bk, bv, Qb, Kb, Vb);
  attn<<<dim3(32, 32), 256, 0, stream>>>(Qb, Kb, Vb, mask, out);
}

// Round 2
// 218.432 us; speedup vs baseline: 1.3898x; 1.3898x over previous
//
#include <hip/hip_runtime.h>

typedef __attribute__((ext_vector_type(4))) float f32x4;
typedef __attribute__((ext_vector_type(8))) short bf16x8;

__device__ __forceinline__ ushort f2bf(float f) {
  union { float f; unsigned u; } v; v.f = f;
  unsigned u = v.u;
  return (ushort)((u + 0x7fffu + ((u >> 16) & 1u)) >> 16);
}

// ---------------- X fp32 -> bf16 ----------------
__global__ __launch_bounds__(256) void cvt_x(const float* __restrict__ x,
                                             ushort* __restrict__ o) {
  int idx = blockIdx.x * 256 + threadIdx.x;
  float4 v = reinterpret_cast<const float4*>(x)[idx];
  ushort4 r;
  r.x = f2bf(v.x); r.y = f2bf(v.y); r.z = f2bf(v.z); r.w = f2bf(v.w);
  reinterpret_cast<ushort4*>(o)[idx] = r;
}

// ---------------- W fp32 [K][N] -> bf16 W^T [3][N][K] ----------------
__global__ __launch_bounds__(256) void wtrans(const float* __restrict__ Wq,
                                              const float* __restrict__ Wk,
                                              const float* __restrict__ Wv,
                                              ushort* __restrict__ WT) {
  __shared__ ushort tile[64 * 65];
  int bx = blockIdx.x;
  int w = bx >> 8;
  int rem = bx & 255;
  int k0 = (rem >> 4) << 6;
  int n0 = (rem & 15) << 6;
  const float* W = (w == 0) ? Wq : (w == 1) ? Wk : Wv;
  int tid = threadIdx.x;
#pragma unroll
  for (int it = 0; it < 16; ++it) {
    int idx = tid + it * 256;
    int r = idx >> 6, c = idx & 63;
    tile[r * 65 + c] = f2bf(W[(k0 + r) * 1024 + n0 + c]);
  }
  __syncthreads();
#pragma unroll
  for (int it = 0; it < 16; ++it) {
    int idx = tid + it * 256;
    int r = idx >> 6, c = idx & 63;
    WT[w * 1048576 + (n0 + r) * 1024 + k0 + c] = tile[c * 65 + r];
  }
}

// ---------------- fused QKV GEMM: 128x128 tile, V written transposed ---------
// grid: (M/128, 3N/128) = (32, 24); block 256 (4 waves as 2x2, each 64x64)
__global__ __launch_bounds__(256) void qkv_gemm(
    const ushort* __restrict__ Xb, const ushort* __restrict__ WT,
    const float* __restrict__ bq, const float* __restrict__ bk,
    const float* __restrict__ bv, ushort* __restrict__ Qb,
    ushort* __restrict__ Kb, ushort* __restrict__ VT) {
  __shared__ ushort Xs[128 * 72];
  __shared__ ushort Ws[128 * 72];
  int tid = threadIdx.x;
  int wave = tid >> 6, lane = tid & 63, g = lane >> 4, lr = lane & 15;
  int wr = wave >> 1, wc = wave & 1;
  int m0 = blockIdx.x << 7;
  int n0g = blockIdx.y << 7;
  f32x4 acc[4][4];
#pragma unroll
  for (int i = 0; i < 4; ++i)
#pragma unroll
    for (int j = 0; j < 4; ++j) { acc[i][j][0] = 0.f; acc[i][j][1] = 0.f; acc[i][j][2] = 0.f; acc[i][j][3] = 0.f; }

  for (int k0 = 0; k0 < 1024; k0 += 64) {
#pragma unroll
    for (int c = 0; c < 4; ++c) {
      int lin = tid + (c << 8);
      int row = lin >> 3, cc = lin & 7;
      *reinterpret_cast<uint4*>(&Xs[row * 72 + cc * 8]) =
          *reinterpret_cast<const uint4*>(&Xb[(m0 + row) * 1024 + k0 + cc * 8]);
      *reinterpret_cast<uint4*>(&Ws[row * 72 + cc * 8]) =
          *reinterpret_cast<const uint4*>(&WT[(n0g + row) * 1024 + k0 + cc * 8]);
    }
    __syncthreads();
#pragma unroll
    for (int ks = 0; ks < 2; ++ks) {
      bf16x8 a[4], b[4];
#pragma unroll
      for (int mi = 0; mi < 4; ++mi)
        a[mi] = *reinterpret_cast<const bf16x8*>(&Xs[(wr * 64 + mi * 16 + lr) * 72 + ks * 32 + g * 8]);
#pragma unroll
      for (int ni = 0; ni < 4; ++ni)
        b[ni] = *reinterpret_cast<const bf16x8*>(&Ws[(wc * 64 + ni * 16 + lr) * 72 + ks * 32 + g * 8]);
#pragma unroll
      for (int mi = 0; mi < 4; ++mi)
#pragma unroll
        for (int ni = 0; ni < 4; ++ni)
          acc[mi][ni] = __builtin_amdgcn_mfma_f32_16x16x32_bf16(a[mi], b[ni], acc[mi][ni], 0, 0, 0);
    }
    __syncthreads();
  }
  int which = n0g >> 10;
  const float* bias = (which == 0) ? bq : (which == 1) ? bk : bv;
  int nb = (n0g & 1023) + wc * 64;
#pragma unroll
  for (int ni = 0; ni < 4; ++ni) {
    int n = nb + ni * 16 + lr;
    float bb = bias[n];
    int hh = n >> 6, dd = n & 63;
#pragma unroll
    for (int mi = 0; mi < 4; ++mi) {
      int mbase = m0 + wr * 64 + mi * 16 + g * 4;
      int b_ = mbase >> 11, s = mbase & 2047;
      if (which == 2) {
        ushort4 v4;
        v4.x = f2bf(acc[mi][ni][0] + bb);
        v4.y = f2bf(acc[mi][ni][1] + bb);
        v4.z = f2bf(acc[mi][ni][2] + bb);
        v4.w = f2bf(acc[mi][ni][3] + bb);
        *reinterpret_cast<ushort4*>(&VT[((size_t)(b_ * 16 + hh) * 64 + dd) * 2048 + s]) = v4;
      } else {
        ushort* ob = (which == 0) ? Qb : Kb;
#pragma unroll
        for (int r = 0; r < 4; ++r)
          ob[((size_t)(b_ * 16 + hh) * 2048 + s + r) * 64 + dd] = f2bf(acc[mi][ni][r] + bb);
      }
    }
  }
}

// ---------------- flash attention (causal, triangle-paired) ----------------
struct QTState {
  f32x4 o[4];
  float m[4], l[4];
};

__device__ __forceinline__ void attn_process(
    const ushort* Ks, const ushort* VsT, ushort* Psw,
    const bf16x8& aq0, const bf16x8& aq1, QTState& st,
    int g, int lr, int qw, int kv0, bool diag, const float* mv) {
  f32x4 sc[4];
#pragma unroll
  for (int sub = 0; sub < 4; ++sub) {
    f32x4 s;
    s[0] = 0.f; s[1] = 0.f; s[2] = 0.f; s[3] = 0.f;
    bf16x8 bk0 = *reinterpret_cast<const bf16x8*>(&Ks[(sub * 16 + lr) * 72 + g * 8]);
    bf16x8 bk1 = *reinterpret_cast<const bf16x8*>(&Ks[(sub * 16 + lr) * 72 + 32 + g * 8]);
    s = __builtin_amdgcn_mfma_f32_16x16x32_bf16(aq0, bk0, s, 0, 0, 0);
    s = __builtin_amdgcn_mfma_f32_16x16x32_bf16(aq1, bk1, s, 0, 0, 0);
    int kk = kv0 + sub * 16 + lr;
#pragma unroll
    for (int r = 0; r < 4; ++r) {
      float v = s[r] * 0.125f + mv[sub];
      if (diag) {
        int q = qw + g * 4 + r;
        v = (kk > q) ? -__builtin_inff() : v;
      }
      s[r] = v;
    }
    sc[sub] = s;
  }
  float alpha[4];
#pragma unroll
  for (int r = 0; r < 4; ++r) {
    float tm = fmaxf(fmaxf(sc[0][r], sc[1][r]), fmaxf(sc[2][r], sc[3][r]));
    tm = fmaxf(tm, __shfl_xor(tm, 1));
    tm = fmaxf(tm, __shfl_xor(tm, 2));
    tm = fmaxf(tm, __shfl_xor(tm, 4));
    tm = fmaxf(tm, __shfl_xor(tm, 8));
    float nm = fmaxf(st.m[r], tm);
    float al = __expf(st.m[r] - nm);
    float rs = 0.f;
#pragma unroll
    for (int sub = 0; sub < 4; ++sub) {
      float p = __expf(sc[sub][r] - nm);
      sc[sub][r] = p;
      rs += p;
    }
    rs += __shfl_xor(rs, 1);
    rs += __shfl_xor(rs, 2);
    rs += __shfl_xor(rs, 4);
    rs += __shfl_xor(rs, 8);
    st.l[r] = st.l[r] * al + rs;
    st.m[r] = nm;
    alpha[r] = al;
#pragma unroll
    for (int sub = 0; sub < 4; ++sub)
      Psw[(g * 4 + r) * 72 + sub * 16 + lr] = f2bf(sc[sub][r]);
  }
#pragma unroll
  for (int ns = 0; ns < 4; ++ns) {
#pragma unroll
    for (int r = 0; r < 4; ++r) st.o[ns][r] *= alpha[r];
  }
#pragma unroll
  for (int kc = 0; kc < 2; ++kc) {
    bf16x8 pa = *reinterpret_cast<const bf16x8*>(&Psw[lr * 72 + kc * 32 + g * 8]);
#pragma unroll
    for (int ds_ = 0; ds_ < 4; ++ds_) {
      bf16x8 vb = *reinterpret_cast<const bf16x8*>(&VsT[(ds_ * 16 + lr) * 72 + kc * 32 + g * 8]);
      st.o[ds_] = __builtin_amdgcn_mfma_f32_16x16x32_bf16(pa, vb, st.o[ds_], 0, 0, 0);
    }
  }
}

// grid: (16, 32); block i handles q-tiles i and 31-i (shared K/V staging)
__global__ __launch_bounds__(256) void attn(const ushort* __restrict__ Qb,
                                            const ushort* __restrict__ Kb,
                                            const ushort* __restrict__ VT,
                                            const float* __restrict__ mask,
                                            float* __restrict__ out) {
  __shared__ ushort Ks[64 * 72];
  __shared__ ushort VsT[64 * 72];   // [d][kv], staged from global V^T
  __shared__ ushort Ps[4][16 * 72];
  int tid = threadIdx.x;
  int wave = tid >> 6, lane = tid & 63, g = lane >> 4, lr = lane & 15;
  int pi = blockIdx.x, bh = blockIdx.y;
  int b_ = bh >> 4, h = bh & 15;
  int qa_t = pi, qb_t = 31 - pi;
  const ushort* Qh = Qb + (size_t)bh * 2048 * 64;
  const ushort* Kh = Kb + (size_t)bh * 2048 * 64;
  const ushort* VTh = VT + (size_t)bh * 64 * 2048;
  int qa_w = qa_t * 64 + wave * 16;
  int qb_w = qb_t * 64 + wave * 16;

  bf16x8 aqa0 = *reinterpret_cast<const bf16x8*>(&Qh[(qa_w + lr) * 64 + g * 8]);
  bf16x8 aqa1 = *reinterpret_cast<const bf16x8*>(&Qh[(qa_w + lr) * 64 + 32 + g * 8]);
  bf16x8 aqb0 = *reinterpret_cast<const bf16x8*>(&Qh[(qb_w + lr) * 64 + g * 8]);
  bf16x8 aqb1 = *reinterpret_cast<const bf16x8*>(&Qh[(qb_w + lr) * 64 + 32 + g * 8]);

  QTState sa, sb;
#pragma unroll
  for (int i = 0; i < 4; ++i) {
    sa.o[i][0] = 0.f; sa.o[i][1] = 0.f; sa.o[i][2] = 0.f; sa.o[i][3] = 0.f;
    sb.o[i][0] = 0.f; sb.o[i][1] = 0.f; sb.o[i][2] = 0.f; sb.o[i][3] = 0.f;
    sa.m[i] = -__builtin_inff(); sa.l[i] = 0.f;
    sb.m[i] = -__builtin_inff(); sb.l[i] = 0.f;
  }
  ushort* Psw = Ps[wave];

  for (int t = 0; t <= qb_t; ++t) {
    int kv0 = t << 6;
#pragma unroll
    for (int c = 0; c < 2; ++c) {
      int lin = tid + (c << 8);
      int row = lin >> 3, cc = lin & 7;
      *reinterpret_cast<uint4*>(&Ks[row * 72 + cc * 8]) =
          *reinterpret_cast<const uint4*>(&Kh[(kv0 + row) * 64 + cc * 8]);
      *reinterpret_cast<uint4*>(&VsT[row * 72 + cc * 8]) =
          *reinterpret_cast<const uint4*>(&VTh[row * 2048 + kv0 + cc * 8]);
    }
    float mv[4];
#pragma unroll
    for (int sub = 0; sub < 4; ++sub) mv[sub] = mask[b_ * 2048 + kv0 + sub * 16 + lr];
    __syncthreads();
    if (t <= qa_t)
      attn_process(Ks, VsT, Psw, aqa0, aqa1, sa, g, lr, qa_w, kv0, t == qa_t, mv);
    attn_process(Ks, VsT, Psw, aqb0, aqb1, sb, g, lr, qb_w, kv0, t == qb_t, mv);
    __syncthreads();
  }

#pragma unroll
  for (int ns = 0; ns < 4; ++ns) {
#pragma unroll
    for (int r = 0; r < 4; ++r) {
      int qa = qa_w + g * 4 + r;
      out[(size_t)(b_ * 2048 + qa) * 1024 + h * 64 + ns * 16 + lr] = sa.o[ns][r] / sa.l[r];
      int qb = qb_w + g * 4 + r;
      out[(size_t)(b_ * 2048 + qb) * 1024 + h * 64 + ns * 16 + lr] = sb.o[ns][r] / sb.l[r];
    }
  }
}

extern "C" void kernel_launch(void* const* d_in, const int* in_sizes, int n_in,
                              void* d_out, int out_size, void* d_ws, size_t ws_size,
                              hipStream_t stream) {
  const float* X    = (const float*)d_in[0];
  const float* mask = (const float*)d_in[1];
  const float* Wq   = (const float*)d_in[2];
  const float* bq   = (const float*)d_in[3];
  const float* Wk   = (const float*)d_in[4];
  const float* bk   = (const float*)d_in[5];
  const float* Wv   = (const float*)d_in[6];
  const float* bv   = (const float*)d_in[7];
  float* out = (float*)d_out;

  char* ws = (char*)d_ws;
  ushort* Xb  = (ushort*)ws;                         // 8 MB
  ushort* WTb = (ushort*)(ws + 8388608);             // 6 MB
  ushort* Qb  = (ushort*)(ws + 8388608 + 6291456);   // 8 MB
  ushort* Kb  = Qb + 4194304;                        // 8 MB
  ushort* VT  = Kb + 4194304;                        // 8 MB  [bh][d][S]

  cvt_x<<<4096, 256, 0, stream>>>(X, Xb);
  wtrans<<<768, 256, 0, stream>>>(Wq, Wk, Wv, WTb);
  qkv_gemm<<<dim3(32, 24), 256, 0, stream>>>(Xb, WTb, bq, bk, bv, Qb, Kb, VT);
  attn<<<dim3(16, 32), 256, 0, stream>>>(Qb, Kb, VT, mask, out);
}